// Round 9
// baseline (1440.766 us; speedup 1.0000x reference)
//
#include <hip/hip_runtime.h>
#include <math.h>

#define G      1708
#define GP     1728         // padded per-head row stride
#define C4     427          // float4 chunks per row
#define NH     5
#define NB     16
#define NC     34
#define JSL    8            // j-slices per i-group
#define ITR    3            // i rows per thread (12 acc floats -> no spill, r5-proven)
#define IPB    96           // rows per block = (256/JSL)*ITR
#define ICH    18           // ceil(G/IPB); 18*96=1728 >= 1708
#define NBLK   (ICH * NH * NB)   // 1440 blocks: co-resident even at 6 blocks/CU (1536)
#define LN_EPS 1e-6f
#define LOG2E  1.4426950408889634f

// ---------------------------------------------------------------------------
// Persistent single-kernel network, round 2.  r8's failure was the
// single-counter grid barrier: 7040 contended cross-XCD atomic RMWs ~= 1.05ms
// (measured 1.08ms, VALUBusy 9.6%).  Replaced with arrival-flags + master
// scan + single go-flag broadcast: zero RMW contention, read-only polling.
// Geometry reverted to no-spill ITR=3 (r8's ITR=5 spilled: WRITE 36MB).
// ---------------------------------------------------------------------------

__device__ __forceinline__ void grid_barrier(
    unsigned* __restrict__ flags, unsigned* __restrict__ go,
    int bid, int tid, unsigned phase)
{
    __syncthreads();
    __threadfence();    // agent-scope release of this block's global writes
    if (tid == 0)
        __hip_atomic_store(&flags[bid], phase, __ATOMIC_RELEASE,
                           __HIP_MEMORY_SCOPE_AGENT);
    if (bid == 0) {
        // master: 256 threads scan all arrival flags (6 each), then broadcast
        for (int i = tid; i < NBLK; i += 256)
            while (__hip_atomic_load(&flags[i], __ATOMIC_ACQUIRE,
                                     __HIP_MEMORY_SCOPE_AGENT) < phase)
                __builtin_amdgcn_s_sleep(4);
        __syncthreads();
        if (tid == 0)
            __hip_atomic_store(go, phase, __ATOMIC_RELEASE,
                               __HIP_MEMORY_SCOPE_AGENT);
    }
    if (tid == 0)
        while (__hip_atomic_load(go, __ATOMIC_ACQUIRE,
                                 __HIP_MEMORY_SCOPE_AGENT) < phase)
            __builtin_amdgcn_s_sleep(4);
    __syncthreads();
    __threadfence();    // acquire side: invalidate caches before reading peers' data
}

// One attention layer for this block's (ic,h,b).  Combined heads of the
// previous layer held in registers (acc0/acc1); k/v tables in LDS; phase-C
// math row-for-row identical to the r0-proven kernel (JSL lanes per row).
template <bool FIRST>
__device__ __forceinline__ void layer_body(
    int ic, int h, int b, int tid,
    const float* __restrict__ hprev, const float* __restrict__ php,
    const float* __restrict__ lna, const float* __restrict__ lnb,
    const float* __restrict__ WQ, const float* __restrict__ WK,
    const float* __restrict__ WV, const float* __restrict__ W0,
    float* __restrict__ ph, float* __restrict__ hcur,
    float* krow, float* vrow, float* hq, float* red)
{
    const int base = ic * IPB;
    const float4* hp4 = reinterpret_cast<const float4*>(hprev + (size_t)b * G);
    float4* kr4 = reinterpret_cast<float4*>(krow);
    float4* vr4 = reinterpret_cast<float4*>(vrow);

    // ---- phase A: combine heads (regs) + LN stats ----
    float4 acc0, acc1;
    float mean = 0.f, inv = 0.f;
    if constexpr (!FIRST) {
        const float4* p0 = reinterpret_cast<const float4*>(php + ((size_t)b * NH + 0) * GP);
        const float4* p1 = reinterpret_cast<const float4*>(php + ((size_t)b * NH + 1) * GP);
        const float4* p2 = reinterpret_cast<const float4*>(php + ((size_t)b * NH + 2) * GP);
        const float4* p3 = reinterpret_cast<const float4*>(php + ((size_t)b * NH + 3) * GP);
        const float4* p4 = reinterpret_cast<const float4*>(php + ((size_t)b * NH + 4) * GP);
        float s = 0.f, ss = 0.f;
        {   // it = 0: c = tid < 256 <= C4, no guard
            const int c = tid;
            float4 a = p0[c], t;
            t = p1[c]; a.x += t.x; a.y += t.y; a.z += t.z; a.w += t.w;
            t = p2[c]; a.x += t.x; a.y += t.y; a.z += t.z; a.w += t.w;
            t = p3[c]; a.x += t.x; a.y += t.y; a.z += t.z; a.w += t.w;
            t = p4[c]; a.x += t.x; a.y += t.y; a.z += t.z; a.w += t.w;
            acc0 = a;
            s  += (a.x + a.y) + (a.z + a.w);
            ss += (a.x * a.x + a.y * a.y) + (a.z * a.z + a.w * a.w);
        }
        {   // it = 1
            const int c = tid + 256;
            if (c < C4) {
                float4 a = p0[c], t;
                t = p1[c]; a.x += t.x; a.y += t.y; a.z += t.z; a.w += t.w;
                t = p2[c]; a.x += t.x; a.y += t.y; a.z += t.z; a.w += t.w;
                t = p3[c]; a.x += t.x; a.y += t.y; a.z += t.z; a.w += t.w;
                t = p4[c]; a.x += t.x; a.y += t.y; a.z += t.z; a.w += t.w;
                acc1 = a;
                s  += (a.x + a.y) + (a.z + a.w);
                ss += (a.x * a.x + a.y * a.y) + (a.z * a.z + a.w * a.w);
            }
        }
        for (int o = 1; o < 64; o <<= 1) {
            s  += __shfl_xor(s, o);
            ss += __shfl_xor(ss, o);
        }
        if ((tid & 63) == 0) { red[tid >> 6] = s; red[4 + (tid >> 6)] = ss; }
        __syncthreads();
        float S  = (red[0] + red[1]) + (red[2] + red[3]);
        float SS = (red[4] + red[5]) + (red[6] + red[7]);
        mean = S / (float)G;
        float var = fmaxf((SS - S * mean) / (float)(G - 1), 0.f);
        inv = 1.f / (sqrtf(var) + LN_EPS);
    }

    // ---- phase B: h values (regs), k/v tables in LDS, block kmin/kmax ----
    const float4* ga4 = reinterpret_cast<const float4*>(lna);
    const float4* gb4 = reinterpret_cast<const float4*>(lnb);
    const float4* wk4 = reinterpret_cast<const float4*>(WK + (size_t)h * G);
    const float4* wv4 = reinterpret_cast<const float4*>(WV + (size_t)h * G);
    float4* hc4 = (!FIRST && hcur != nullptr && h == 0 && ic == 0)
                      ? reinterpret_cast<float4*>(hcur + (size_t)b * G) : nullptr;

    float kmx = -INFINITY, kmn = INFINITY;
#pragma unroll
    for (int it = 0; it < 2; ++it) {
        const int c = tid + it * 256;
        if (it == 0 || c < C4) {
            float4 hv;
            if constexpr (FIRST) {
                hv = hp4[c];
            } else {
                float4 a = (it == 0) ? acc0 : acc1;
                float4 hp = hp4[c], ga = ga4[c], gb = gb4[c];
                hv.x = hp.x + ga.x * (a.x - mean) * inv + gb.x;
                hv.y = hp.y + ga.y * (a.y - mean) * inv + gb.y;
                hv.z = hp.z + ga.z * (a.z - mean) * inv + gb.z;
                hv.w = hp.w + ga.w * (a.w - mean) * inv + gb.w;
            }
            if (hc4) hc4[c] = hv;
            float4 wk = wk4[c], wv = wv4[c], kl, vv;
            kl.x = hv.x * wk.x * LOG2E; kl.y = hv.y * wk.y * LOG2E;
            kl.z = hv.z * wk.z * LOG2E; kl.w = hv.w * wk.w * LOG2E;
            vv.x = hv.x * wv.x; vv.y = hv.y * wv.y;
            vv.z = hv.z * wv.z; vv.w = hv.w * wv.w;
            kr4[c] = kl;
            vr4[c] = vv;
            kmx = fmaxf(kmx, fmaxf(fmaxf(kl.x, kl.y), fmaxf(kl.z, kl.w)));
            kmn = fminf(kmn, fminf(fminf(kl.x, kl.y), fminf(kl.z, kl.w)));
            // stash h values this block needs for q
            const int r0 = (c << 2) - base;
            if (r0 >= -3 && r0 < IPB) {
                if ((unsigned)r0       < (unsigned)IPB) hq[r0]     = hv.x;
                if ((unsigned)(r0 + 1) < (unsigned)IPB) hq[r0 + 1] = hv.y;
                if ((unsigned)(r0 + 2) < (unsigned)IPB) hq[r0 + 2] = hv.z;
                if ((unsigned)(r0 + 3) < (unsigned)IPB) hq[r0 + 3] = hv.w;
            }
        }
    }
    for (int o = 1; o < 64; o <<= 1) {
        kmx = fmaxf(kmx, __shfl_xor(kmx, o));
        kmn = fminf(kmn, __shfl_xor(kmn, o));
    }
    if ((tid & 63) == 0) { red[8 + (tid >> 6)] = kmx; red[12 + (tid >> 6)] = kmn; }
    __syncthreads();   // k/v/hq tables + red[8..15] visible
    kmx = fmaxf(fmaxf(red[8], red[9]),  fmaxf(red[10], red[11]));
    kmn = fminf(fminf(red[12], red[13]), fminf(red[14], red[15]));

    // ---- phase C: softmax-weighted sums over j (8 lanes per row, 3 rows) --
    const int ig = tid >> 3, sl = tid & 7;
    const int i0 = base + ig * ITR;
    const float* wqg = WQ + (size_t)h * G;

    float q[ITR], nm[ITR], S1[ITR], S2[ITR];
#pragma unroll
    for (int r = 0; r < ITR; ++r) {
        const int row = i0 + r;
        const int rs = row < G ? row : G - 1;
        const float qv = hq[rs - base] * wqg[rs];
        q[r]  = qv;
        nm[r] = -fmaxf(qv * kmx, qv * kmn);   // exact rank-1 row max
        S1[r] = 0.f;
        S2[r] = 0.f;
    }

#pragma unroll 2
    for (int c = sl; c < C4; c += JSL) {
        const float4 kk = kr4[c];
        const float4 vq = vr4[c];
#pragma unroll
        for (int r = 0; r < ITR; ++r) {
            const float qq = q[r], mm = nm[r];
            float e0 = __builtin_amdgcn_exp2f(fmaf(qq, kk.x, mm));
            float e1 = __builtin_amdgcn_exp2f(fmaf(qq, kk.y, mm));
            float e2 = __builtin_amdgcn_exp2f(fmaf(qq, kk.z, mm));
            float e3 = __builtin_amdgcn_exp2f(fmaf(qq, kk.w, mm));
            S1[r] += (e0 + e1) + (e2 + e3);
            S2[r] += (e0 * vq.x + e1 * vq.y) + (e2 * vq.z + e3 * vq.w);
        }
    }

#pragma unroll
    for (int r = 0; r < ITR; ++r) {
        S1[r] += __shfl_xor(S1[r], 1);
        S1[r] += __shfl_xor(S1[r], 2);
        S1[r] += __shfl_xor(S1[r], 4);
        S2[r] += __shfl_xor(S2[r], 1);
        S2[r] += __shfl_xor(S2[r], 2);
        S2[r] += __shfl_xor(S2[r], 4);
    }

    if (sl == 0) {
        const float w0h = W0[h];
        float* pout = ph + ((size_t)b * NH + h) * GP;
#pragma unroll
        for (int r = 0; r < ITR; ++r) {
            const int row = i0 + r;
            if (row < G) {
                float eii = __builtin_amdgcn_exp2f(fmaf(q[r], krow[row], nm[r]));
                pout[row] = w0h * (S2[r] - eii * vrow[row]) / S1[r];
            }
        }
    }
}

// One logit (c,b): recombine layer-3 heads + LN on the fly, dot with fc row.
__device__ __forceinline__ void logits_body(
    int c, int b, int tid,
    const float* __restrict__ hprev, const float* __restrict__ php,
    const float* __restrict__ lna, const float* __restrict__ lnb,
    const float* __restrict__ fcw, const float* __restrict__ fcb,
    float* __restrict__ lgt, float* arow, float* red)
{
    const float4* p0 = reinterpret_cast<const float4*>(php + ((size_t)b * NH + 0) * GP);
    const float4* p1 = reinterpret_cast<const float4*>(php + ((size_t)b * NH + 1) * GP);
    const float4* p2 = reinterpret_cast<const float4*>(php + ((size_t)b * NH + 2) * GP);
    const float4* p3 = reinterpret_cast<const float4*>(php + ((size_t)b * NH + 3) * GP);
    const float4* p4 = reinterpret_cast<const float4*>(php + ((size_t)b * NH + 4) * GP);
    float4* ar4 = reinterpret_cast<float4*>(arow);

    float s = 0.f, ss = 0.f;
    for (int k = tid; k < C4; k += 256) {
        float4 a = p0[k], t;
        t = p1[k]; a.x += t.x; a.y += t.y; a.z += t.z; a.w += t.w;
        t = p2[k]; a.x += t.x; a.y += t.y; a.z += t.z; a.w += t.w;
        t = p3[k]; a.x += t.x; a.y += t.y; a.z += t.z; a.w += t.w;
        t = p4[k]; a.x += t.x; a.y += t.y; a.z += t.z; a.w += t.w;
        ar4[k] = a;
        s  += (a.x + a.y) + (a.z + a.w);
        ss += (a.x * a.x + a.y * a.y) + (a.z * a.z + a.w * a.w);
    }
    for (int o = 1; o < 64; o <<= 1) {
        s  += __shfl_xor(s, o);
        ss += __shfl_xor(ss, o);
    }
    if ((tid & 63) == 0) { red[tid >> 6] = s; red[4 + (tid >> 6)] = ss; }
    __syncthreads();
    float S  = (red[0] + red[1]) + (red[2] + red[3]);
    float SS = (red[4] + red[5]) + (red[6] + red[7]);
    const float mean = S / (float)G;
    const float var  = fmaxf((SS - S * mean) / (float)(G - 1), 0.f);
    const float inv  = 1.f / (sqrtf(var) + LN_EPS);

    const float4* hp4 = reinterpret_cast<const float4*>(hprev + (size_t)b * G);
    const float4* ga4 = reinterpret_cast<const float4*>(lna);
    const float4* gb4 = reinterpret_cast<const float4*>(lnb);
    const float4* w4  = reinterpret_cast<const float4*>(fcw + (size_t)c * G);
    float acc = 0.f;
    for (int k = tid; k < C4; k += 256) {
        float4 a = ar4[k], hp = hp4[k], ga = ga4[k], gb = gb4[k], w = w4[k];
        float hx = hp.x + ga.x * (a.x - mean) * inv + gb.x;
        float hy = hp.y + ga.y * (a.y - mean) * inv + gb.y;
        float hz = hp.z + ga.z * (a.z - mean) * inv + gb.z;
        float hw = hp.w + ga.w * (a.w - mean) * inv + gb.w;
        acc += (hx * w.x + hy * w.y) + (hz * w.z + hw * w.w);
    }
    for (int o = 1; o < 64; o <<= 1) acc += __shfl_xor(acc, o);
    __syncthreads();
    if ((tid & 63) == 0) red[tid >> 6] = acc;
    __syncthreads();
    if (tid == 0)
        lgt[(size_t)b * NC + c] =
            (red[0] + red[1]) + (red[2] + red[3]) + fcb[c];
}

__global__ __launch_bounds__(256, 8) void mynet_persistent(
    const float* __restrict__ x,
    const float* __restrict__ WQ1, const float* __restrict__ WK1,
    const float* __restrict__ WV1, const float* __restrict__ W01,
    const float* __restrict__ WQ2, const float* __restrict__ WK2,
    const float* __restrict__ WV2, const float* __restrict__ W02,
    const float* __restrict__ WQ3, const float* __restrict__ WK3,
    const float* __restrict__ WV3, const float* __restrict__ W03,
    const float* __restrict__ lna, const float* __restrict__ lnb,
    const float* __restrict__ fcw, const float* __restrict__ fcb,
    float* __restrict__ pha, float* __restrict__ phb,
    float* __restrict__ h1, float* __restrict__ h2,
    float* __restrict__ lgt, unsigned* __restrict__ flags,
    unsigned* __restrict__ go, float* __restrict__ out)
{
    __shared__ __align__(16) float krow[G];
    __shared__ __align__(16) float vrow[G];
    __shared__ float hq[IPB];
    __shared__ float red[16];

    const int bid = blockIdx.x, tid = threadIdx.x;
    const int ic = bid % ICH;
    const int h  = (bid / ICH) % NH;
    const int b  = bid / (ICH * NH);

    // layer 1: heads(x) -> pha
    layer_body<true>(ic, h, b, tid, x, nullptr, lna, lnb,
                     WQ1, WK1, WV1, W01, pha, nullptr, krow, vrow, hq, red);
    grid_barrier(flags, go, bid, tid, 1u);

    // layer 2: h1 = x + LN(combine(pha)); heads -> phb
    layer_body<false>(ic, h, b, tid, x, pha, lna, lnb,
                      WQ2, WK2, WV2, W02, phb, h1, krow, vrow, hq, red);
    grid_barrier(flags, go, bid, tid, 2u);

    // layer 3: h2 = h1 + LN(combine(phb)); heads -> pha
    layer_body<false>(ic, h, b, tid, h1, phb, lna, lnb,
                      WQ3, WK3, WV3, W03, pha, h2, krow, vrow, hq, red);
    grid_barrier(flags, go, bid, tid, 3u);

    // logits: 544 blocks, one (c,b) each; h3 = h2 + LN(combine(pha))
    if (bid < NC * NB)
        logits_body(bid % NC, bid / NC, tid, h2, pha, lna, lnb,
                    fcw, fcb, lgt, krow, red);
    grid_barrier(flags, go, bid, tid, 4u);

    // log_softmax: blocks 0..15, first wave each
    if (bid < NB && tid < 64) {
        float l = (tid < NC) ? lgt[(size_t)bid * NC + tid] : -INFINITY;
        float mm = l;
        for (int o = 32; o; o >>= 1) mm = fmaxf(mm, __shfl_xor(mm, o));
        float e = (tid < NC) ? expf(l - mm) : 0.f;
        float se = e;
        for (int o = 32; o; o >>= 1) se += __shfl_xor(se, o);
        if (tid < NC) out[(size_t)bid * NC + tid] = l - mm - logf(se);
    }
}

// ---------------------------------------------------------------------------
extern "C" void kernel_launch(void* const* d_in, const int* in_sizes, int n_in,
                              void* d_out, int out_size, void* d_ws, size_t ws_size,
                              hipStream_t stream)
{
    const float* x    = (const float*)d_in[0];
    const float* WQ1  = (const float*)d_in[1];
    const float* WK1  = (const float*)d_in[2];
    const float* WV1  = (const float*)d_in[3];
    const float* W01  = (const float*)d_in[4];
    const float* WQ2  = (const float*)d_in[5];
    const float* WK2  = (const float*)d_in[6];
    const float* WV2  = (const float*)d_in[7];
    const float* W02  = (const float*)d_in[8];
    const float* WQ3  = (const float*)d_in[9];
    const float* WK3  = (const float*)d_in[10];
    const float* WV3  = (const float*)d_in[11];
    const float* W03  = (const float*)d_in[12];
    const float* lna  = (const float*)d_in[13];
    const float* lnb  = (const float*)d_in[14];
    const float* fcw  = (const float*)d_in[15];
    const float* fcb  = (const float*)d_in[16];
    float* out = (float*)d_out;

    const size_t PHS = (size_t)NB * NH * GP;
    unsigned* flags = (unsigned*)d_ws;                // [NBLK] arrival flags
    unsigned* go    = flags + 2000;                   // broadcast flag (own line)
    float* pha = (float*)d_ws + 2048;                 // layer 1 / 3 head rows
    float* phb = pha + PHS;                           // layer 2 head rows
    float* h1  = phb + PHS;                           // [NB,G]
    float* h2  = h1 + (size_t)NB * G;                 // [NB,G]
    float* lgt = h2 + (size_t)NB * G;                 // [NB,NC]

    hipMemsetAsync(flags, 0, 8192, stream);           // flags + go
    mynet_persistent<<<NBLK, 256, 0, stream>>>(
        x, WQ1, WK1, WV1, W01, WQ2, WK2, WV2, W02, WQ3, WK3, WV3, W03,
        lna, lnb, fcw, fcb, pha, phb, h1, h2, lgt, flags, go, out);
}

// Round 11
// 213.088 us; speedup vs baseline: 6.7614x; 6.7614x over previous
//
#include <hip/hip_runtime.h>
#include <math.h>

#define G      1708
#define GP     1728         // padded per-head row stride
#define C4     427          // float4 chunks per row
#define NH     5
#define NB     16
#define NC     34
#define JSL    8            // j-slices per i-group
#define ITR    3            // i rows per thread (12 acc floats -> no spill, proven r9)
#define IPB    96           // rows per block = (256/JSL)*ITR
#define ICH    18           // ceil(G/IPB); 18*96=1728 >= 1708
#define LN_EPS 1e-6f
#define LOG2E  1.4426950408889634f

// ---------------------------------------------------------------------------
// attn_layer: grid (18,5,16) = 1440 blocks <= 1792 resident (7 blocks/CU at
// 14.3KB LDS; launch_bounds(256,8) caps VGPR at 64, measured 32 in r9).
// Single residency round (no 3-round x 80%-fill quantization of the 4320-
// block r6 variant) and prep redundancy cut 54x -> 18x per (b,h).
// layer_body math is byte-identical to r9's correctness-proven kernel.
// ---------------------------------------------------------------------------
template <bool FIRST>
__global__ __launch_bounds__(256, 8) void attn_layer(
    const float* __restrict__ hprev, const float* __restrict__ php,
    const float* __restrict__ lna, const float* __restrict__ lnb,
    const float* __restrict__ WQ, const float* __restrict__ WK,
    const float* __restrict__ WV, const float* __restrict__ W0,
    float* __restrict__ ph, float* __restrict__ hcur)
{
    __shared__ __align__(16) float krow[G];
    __shared__ __align__(16) float vrow[G];
    __shared__ float hq[IPB];
    __shared__ float red[16];

    const int ic = blockIdx.x, h = blockIdx.y, b = blockIdx.z;
    const int tid = threadIdx.x;
    const int base = ic * IPB;

    const float4* hp4 = reinterpret_cast<const float4*>(hprev + (size_t)b * G);
    float4* kr4 = reinterpret_cast<float4*>(krow);
    float4* vr4 = reinterpret_cast<float4*>(vrow);

    // ---- phase A: combine heads (regs) + LN stats ----
    float4 acc0, acc1;
    float mean = 0.f, inv = 0.f;
    if constexpr (!FIRST) {
        const float4* p0 = reinterpret_cast<const float4*>(php + ((size_t)b * NH + 0) * GP);
        const float4* p1 = reinterpret_cast<const float4*>(php + ((size_t)b * NH + 1) * GP);
        const float4* p2 = reinterpret_cast<const float4*>(php + ((size_t)b * NH + 2) * GP);
        const float4* p3 = reinterpret_cast<const float4*>(php + ((size_t)b * NH + 3) * GP);
        const float4* p4 = reinterpret_cast<const float4*>(php + ((size_t)b * NH + 4) * GP);
        float s = 0.f, ss = 0.f;
        {   // it = 0: c = tid < 256 <= C4, no guard
            const int c = tid;
            float4 a = p0[c], t;
            t = p1[c]; a.x += t.x; a.y += t.y; a.z += t.z; a.w += t.w;
            t = p2[c]; a.x += t.x; a.y += t.y; a.z += t.z; a.w += t.w;
            t = p3[c]; a.x += t.x; a.y += t.y; a.z += t.z; a.w += t.w;
            t = p4[c]; a.x += t.x; a.y += t.y; a.z += t.z; a.w += t.w;
            acc0 = a;
            s  += (a.x + a.y) + (a.z + a.w);
            ss += (a.x * a.x + a.y * a.y) + (a.z * a.z + a.w * a.w);
        }
        {   // it = 1
            const int c = tid + 256;
            if (c < C4) {
                float4 a = p0[c], t;
                t = p1[c]; a.x += t.x; a.y += t.y; a.z += t.z; a.w += t.w;
                t = p2[c]; a.x += t.x; a.y += t.y; a.z += t.z; a.w += t.w;
                t = p3[c]; a.x += t.x; a.y += t.y; a.z += t.z; a.w += t.w;
                t = p4[c]; a.x += t.x; a.y += t.y; a.z += t.z; a.w += t.w;
                acc1 = a;
                s  += (a.x + a.y) + (a.z + a.w);
                ss += (a.x * a.x + a.y * a.y) + (a.z * a.z + a.w * a.w);
            }
        }
        for (int o = 1; o < 64; o <<= 1) {
            s  += __shfl_xor(s, o);
            ss += __shfl_xor(ss, o);
        }
        if ((tid & 63) == 0) { red[tid >> 6] = s; red[4 + (tid >> 6)] = ss; }
        __syncthreads();
        float S  = (red[0] + red[1]) + (red[2] + red[3]);
        float SS = (red[4] + red[5]) + (red[6] + red[7]);
        mean = S / (float)G;
        float var = fmaxf((SS - S * mean) / (float)(G - 1), 0.f);
        inv = 1.f / (sqrtf(var) + LN_EPS);
    }

    // ---- phase B: h values (regs), k/v tables in LDS, block kmin/kmax ----
    const float4* ga4 = reinterpret_cast<const float4*>(lna);
    const float4* gb4 = reinterpret_cast<const float4*>(lnb);
    const float4* wk4 = reinterpret_cast<const float4*>(WK + (size_t)h * G);
    const float4* wv4 = reinterpret_cast<const float4*>(WV + (size_t)h * G);
    float4* hc4 = (!FIRST && hcur != nullptr && h == 0 && ic == 0)
                      ? reinterpret_cast<float4*>(hcur + (size_t)b * G) : nullptr;

    float kmx = -INFINITY, kmn = INFINITY;
#pragma unroll
    for (int it = 0; it < 2; ++it) {
        const int c = tid + it * 256;
        if (it == 0 || c < C4) {
            float4 hv;
            if constexpr (FIRST) {
                hv = hp4[c];
            } else {
                float4 a = (it == 0) ? acc0 : acc1;
                float4 hp = hp4[c], ga = ga4[c], gb = gb4[c];
                hv.x = hp.x + ga.x * (a.x - mean) * inv + gb.x;
                hv.y = hp.y + ga.y * (a.y - mean) * inv + gb.y;
                hv.z = hp.z + ga.z * (a.z - mean) * inv + gb.z;
                hv.w = hp.w + ga.w * (a.w - mean) * inv + gb.w;
            }
            if (hc4) hc4[c] = hv;
            float4 wk = wk4[c], wv = wv4[c], kl, vv;
            kl.x = hv.x * wk.x * LOG2E; kl.y = hv.y * wk.y * LOG2E;
            kl.z = hv.z * wk.z * LOG2E; kl.w = hv.w * wk.w * LOG2E;
            vv.x = hv.x * wv.x; vv.y = hv.y * wv.y;
            vv.z = hv.z * wv.z; vv.w = hv.w * wv.w;
            kr4[c] = kl;
            vr4[c] = vv;
            kmx = fmaxf(kmx, fmaxf(fmaxf(kl.x, kl.y), fmaxf(kl.z, kl.w)));
            kmn = fminf(kmn, fminf(fminf(kl.x, kl.y), fminf(kl.z, kl.w)));
            // stash h values this block needs for q
            const int r0 = (c << 2) - base;
            if (r0 >= -3 && r0 < IPB) {
                if ((unsigned)r0       < (unsigned)IPB) hq[r0]     = hv.x;
                if ((unsigned)(r0 + 1) < (unsigned)IPB) hq[r0 + 1] = hv.y;
                if ((unsigned)(r0 + 2) < (unsigned)IPB) hq[r0 + 2] = hv.z;
                if ((unsigned)(r0 + 3) < (unsigned)IPB) hq[r0 + 3] = hv.w;
            }
        }
    }
    for (int o = 1; o < 64; o <<= 1) {
        kmx = fmaxf(kmx, __shfl_xor(kmx, o));
        kmn = fminf(kmn, __shfl_xor(kmn, o));
    }
    if ((tid & 63) == 0) { red[8 + (tid >> 6)] = kmx; red[12 + (tid >> 6)] = kmn; }
    __syncthreads();   // k/v/hq tables + red[8..15] visible
    kmx = fmaxf(fmaxf(red[8], red[9]),  fmaxf(red[10], red[11]));
    kmn = fminf(fminf(red[12], red[13]), fminf(red[14], red[15]));

    // ---- phase C: softmax-weighted sums over j (8 lanes per row, 3 rows) --
    const int ig = tid >> 3, sl = tid & 7;
    const int i0 = base + ig * ITR;
    const float* wqg = WQ + (size_t)h * G;

    float q[ITR], nm[ITR], S1[ITR], S2[ITR];
#pragma unroll
    for (int r = 0; r < ITR; ++r) {
        const int row = i0 + r;
        const int rs = row < G ? row : G - 1;
        const float qv = hq[rs - base] * wqg[rs];
        q[r]  = qv;
        nm[r] = -fmaxf(qv * kmx, qv * kmn);   // exact rank-1 row max
        S1[r] = 0.f;
        S2[r] = 0.f;
    }

#pragma unroll 2
    for (int c = sl; c < C4; c += JSL) {
        const float4 kk = kr4[c];
        const float4 vq = vr4[c];
#pragma unroll
        for (int r = 0; r < ITR; ++r) {
            const float qq = q[r], mm = nm[r];
            float e0 = __builtin_amdgcn_exp2f(fmaf(qq, kk.x, mm));
            float e1 = __builtin_amdgcn_exp2f(fmaf(qq, kk.y, mm));
            float e2 = __builtin_amdgcn_exp2f(fmaf(qq, kk.z, mm));
            float e3 = __builtin_amdgcn_exp2f(fmaf(qq, kk.w, mm));
            S1[r] += (e0 + e1) + (e2 + e3);
            S2[r] += (e0 * vq.x + e1 * vq.y) + (e2 * vq.z + e3 * vq.w);
        }
    }

#pragma unroll
    for (int r = 0; r < ITR; ++r) {
        S1[r] += __shfl_xor(S1[r], 1);
        S1[r] += __shfl_xor(S1[r], 2);
        S1[r] += __shfl_xor(S1[r], 4);
        S2[r] += __shfl_xor(S2[r], 1);
        S2[r] += __shfl_xor(S2[r], 2);
        S2[r] += __shfl_xor(S2[r], 4);
    }

    if (sl == 0) {
        const float w0h = W0[h];
        float* pout = ph + ((size_t)b * NH + h) * GP;
#pragma unroll
        for (int r = 0; r < ITR; ++r) {
            const int row = i0 + r;
            if (row < G) {
                float eii = __builtin_amdgcn_exp2f(fmaf(q[r], krow[row], nm[r]));
                pout[row] = w0h * (S2[r] - eii * vrow[row]) / S1[r];
            }
        }
    }
}

// ---------------------------------------------------------------------------
// One logit per block: recombine layer-3 heads + LN on the fly, dot with
// fc row c.  grid (NC, NB) = 544 blocks.  (r0/r6-proven, unchanged)
// ---------------------------------------------------------------------------
__global__ __launch_bounds__(256) void logits_kernel(
    const float* __restrict__ hprev, const float* __restrict__ php,
    const float* __restrict__ lna, const float* __restrict__ lnb,
    const float* __restrict__ fcw, const float* __restrict__ fcb,
    float* __restrict__ lgt)
{
    __shared__ __align__(16) float arow[G];
    __shared__ float red[8];
    const int c = blockIdx.x, b = blockIdx.y, tid = threadIdx.x;

    const float4* p0 = reinterpret_cast<const float4*>(php + ((size_t)b * NH + 0) * GP);
    const float4* p1 = reinterpret_cast<const float4*>(php + ((size_t)b * NH + 1) * GP);
    const float4* p2 = reinterpret_cast<const float4*>(php + ((size_t)b * NH + 2) * GP);
    const float4* p3 = reinterpret_cast<const float4*>(php + ((size_t)b * NH + 3) * GP);
    const float4* p4 = reinterpret_cast<const float4*>(php + ((size_t)b * NH + 4) * GP);
    float4* ar4 = reinterpret_cast<float4*>(arow);

    float s = 0.f, ss = 0.f;
    for (int k = tid; k < C4; k += 256) {
        float4 a = p0[k], t;
        t = p1[k]; a.x += t.x; a.y += t.y; a.z += t.z; a.w += t.w;
        t = p2[k]; a.x += t.x; a.y += t.y; a.z += t.z; a.w += t.w;
        t = p3[k]; a.x += t.x; a.y += t.y; a.z += t.z; a.w += t.w;
        t = p4[k]; a.x += t.x; a.y += t.y; a.z += t.z; a.w += t.w;
        ar4[k] = a;
        s  += (a.x + a.y) + (a.z + a.w);
        ss += (a.x * a.x + a.y * a.y) + (a.z * a.z + a.w * a.w);
    }
    for (int o = 1; o < 64; o <<= 1) {
        s  += __shfl_xor(s, o);
        ss += __shfl_xor(ss, o);
    }
    if ((tid & 63) == 0) { red[tid >> 6] = s; red[4 + (tid >> 6)] = ss; }
    __syncthreads();
    float S  = (red[0] + red[1]) + (red[2] + red[3]);
    float SS = (red[4] + red[5]) + (red[6] + red[7]);
    const float mean = S / (float)G;
    const float var  = fmaxf((SS - S * mean) / (float)(G - 1), 0.f);
    const float inv  = 1.f / (sqrtf(var) + LN_EPS);

    const float4* hp4 = reinterpret_cast<const float4*>(hprev + (size_t)b * G);
    const float4* ga4 = reinterpret_cast<const float4*>(lna);
    const float4* gb4 = reinterpret_cast<const float4*>(lnb);
    const float4* w4  = reinterpret_cast<const float4*>(fcw + (size_t)c * G);
    float acc = 0.f;
    for (int k = tid; k < C4; k += 256) {
        float4 a = ar4[k], hp = hp4[k], ga = ga4[k], gb = gb4[k], w = w4[k];
        float hx = hp.x + ga.x * (a.x - mean) * inv + gb.x;
        float hy = hp.y + ga.y * (a.y - mean) * inv + gb.y;
        float hz = hp.z + ga.z * (a.z - mean) * inv + gb.z;
        float hw = hp.w + ga.w * (a.w - mean) * inv + gb.w;
        acc += (hx * w.x + hy * w.y) + (hz * w.z + hw * w.w);
    }
    for (int o = 1; o < 64; o <<= 1) acc += __shfl_xor(acc, o);
    __syncthreads();
    if ((tid & 63) == 0) red[tid >> 6] = acc;
    __syncthreads();
    if (tid == 0)
        lgt[(size_t)b * NC + c] =
            (red[0] + red[1]) + (red[2] + red[3]) + fcb[c];
}

// out = log_softmax(logits) — one wave per batch row  (r0/r6-proven)
__global__ __launch_bounds__(64) void lsm_kernel(
    const float* __restrict__ lgt, float* __restrict__ out)
{
    const int b = blockIdx.x, tid = threadIdx.x;
    float l = (tid < NC) ? lgt[(size_t)b * NC + tid] : -INFINITY;
    float mm = l;
    for (int o = 32; o; o >>= 1) mm = fmaxf(mm, __shfl_xor(mm, o));
    float e = (tid < NC) ? expf(l - mm) : 0.f;
    float se = e;
    for (int o = 32; o; o >>= 1) se += __shfl_xor(se, o);
    if (tid < NC) out[(size_t)b * NC + tid] = l - mm - logf(se);
}

// ---------------------------------------------------------------------------
extern "C" void kernel_launch(void* const* d_in, const int* in_sizes, int n_in,
                              void* d_out, int out_size, void* d_ws, size_t ws_size,
                              hipStream_t stream)
{
    const float* x    = (const float*)d_in[0];
    const float* WQ1  = (const float*)d_in[1];
    const float* WK1  = (const float*)d_in[2];
    const float* WV1  = (const float*)d_in[3];
    const float* W01  = (const float*)d_in[4];
    const float* WQ2  = (const float*)d_in[5];
    const float* WK2  = (const float*)d_in[6];
    const float* WV2  = (const float*)d_in[7];
    const float* W02  = (const float*)d_in[8];
    const float* WQ3  = (const float*)d_in[9];
    const float* WK3  = (const float*)d_in[10];
    const float* WV3  = (const float*)d_in[11];
    const float* W03  = (const float*)d_in[12];
    const float* lna  = (const float*)d_in[13];
    const float* lnb  = (const float*)d_in[14];
    const float* fcw  = (const float*)d_in[15];
    const float* fcb  = (const float*)d_in[16];
    float* out = (float*)d_out;

    const size_t PHS = (size_t)NB * NH * GP;
    float* pha = (float*)d_ws;           // layer 1 / 3 per-head rows
    float* phb = pha + PHS;              // layer 2 per-head rows
    float* h1  = phb + PHS;              // [NB,G]  (combined input of layer 3)
    float* h2  = h1 + (size_t)NB * G;    // [NB,G]  (combined input of logits LN)
    float* lgt = h2 + (size_t)NB * G;    // [NB,NC]

    const dim3 agrid(ICH, NH, NB);       // (18,5,16) = 1440 blocks, 1 round

    attn_layer<true><<<agrid, 256, 0, stream>>>(
        x, nullptr, lna, lnb, WQ1, WK1, WV1, W01, pha, nullptr);
    attn_layer<false><<<agrid, 256, 0, stream>>>(
        x, pha, lna, lnb, WQ2, WK2, WV2, W02, phb, h1);
    attn_layer<false><<<agrid, 256, 0, stream>>>(
        h1, phb, lna, lnb, WQ3, WK3, WV3, W03, pha, h2);
    logits_kernel<<<dim3(NC, NB), 256, 0, stream>>>(
        h2, pha, lna, lnb, fcw, fcb, lgt);
    lsm_kernel<<<NB, 64, 0, stream>>>(lgt, out);
}